// Round 8
// baseline (1463.678 us; speedup 1.0000x reference)
//
#include <hip/hip_runtime.h>
#include <hip/hip_bf16.h>
#include <math.h>

#define Bn 4096
#define Dd 768
#define SC2 28.85390081777927f   // 20 * log2(e): logits kept in base-2 domain
#define EPSF 1e-6f
#define DG 4.8516519541e8f       // expf(20.0f): exact exp_ori diagonal

// ws layout (4-byte elements)
#define O_S      0        // 3*4096 row sums (ori_nodiag, gen, aug)
#define O_SMOA   12288    // same-masked (ori_nodiag + aug) sums
#define O_SMG    16384    // same-masked gen sums
#define ZERO_F   20480    // floats to zero (covers all atomic sums)
#define O_P      20480    // uint: total pairs (= sum cnt^2)
#define O_RM     20608    // uint2[4096]: {tg | rank<<8, rowSlotBase}
#define LIST_OFF   262144      // byte offset: LCAP uint4 pair entries {row,x0,x1,x2}
#define LCAP       (1u << 19)
#define NB_OFF     33554432    // byte offset: bf16 normalized rows on|gn|an

typedef __attribute__((ext_vector_type(8))) short sh8;
typedef __attribute__((ext_vector_type(4))) float f32x4;

#define AS1 __attribute__((address_space(1)))
#define AS3 __attribute__((address_space(3)))

static __device__ __forceinline__ void gl_lds16(const void* g, void* l) {
    __builtin_amdgcn_global_load_lds((const AS1 void*)g, (AS3 void*)l, 16, 0, 0);
}

static __device__ __forceinline__ unsigned short f2b(float f) {
    unsigned int u = __float_as_uint(f);
    unsigned int r = (u + 0x7fffu + ((u >> 16) & 1u)) >> 16;  // RNE
    return (unsigned short)r;
}

// ---- normalize rows (blocks x<4096) + class sort (block x==4096,y==0) ----
__global__ void norm_sort_kernel(const float* f0, const float* f1, const float* f2,
                                 unsigned short* nb, const int* tg, unsigned int* I,
                                 float* out) {
    int r = blockIdx.x, m = blockIdx.y, tid = threadIdx.x;
    if (r == Bn) {
        if (m != 0) return;
        // ---- sort body (256 threads) ----
        float* F = (float*)I;
        __shared__ unsigned int h[128], pb[128], cur[128];
        for (int e = tid; e < ZERO_F; e += 256) F[e] = 0.f;
        if (tid == 0) { out[0] = 0.f; out[1] = 0.f; }
        if (tid < 128) { h[tid] = 0; cur[tid] = 0; }
        __syncthreads();
        for (int e = tid; e < Bn; e += 256) atomicAdd(&h[tg[e]], 1u);
        __syncthreads();
        if (tid < 128) pb[tid] = h[tid] * h[tid];
        __syncthreads();
        for (int s = 1; s < 128; s <<= 1) {
            unsigned int b = 0;
            if (tid < 128 && tid >= s) b = pb[tid - s];
            __syncthreads();
            if (tid < 128) pb[tid] += b;
            __syncthreads();
        }
        if (tid == 127) I[O_P] = pb[127];
        uint2* RM = (uint2*)(I + O_RM);
        for (int e = tid; e < Bn; e += 256) {
            int c = tg[e];
            unsigned int rk = atomicAdd(&cur[c], 1u);
            unsigned int n = h[c];
            RM[e] = make_uint2((unsigned)c | (rk << 8), (pb[c] - n * n) + rk * n);
        }
        return;
    }
    const float* src = (m == 0 ? f0 : (m == 1 ? f1 : f2)) + (size_t)r * Dd;
    float x0 = src[tid], x1 = src[tid + 256], x2 = src[tid + 512];
    float v = x0 * x0 + x1 * x1 + x2 * x2;
    #pragma unroll
    for (int off = 1; off < 64; off <<= 1) v += __shfl_xor(v, off);
    __shared__ float wr[4];
    if ((tid & 63) == 0) wr[tid >> 6] = v;
    __syncthreads();
    float inv = rsqrtf(wr[0] + wr[1] + wr[2] + wr[3]);
    unsigned short* dst = nb + ((size_t)m * Bn + r) * Dd;
    dst[tid] = f2b(x0 * inv);
    dst[tid + 256] = f2b(x1 * inv);
    dst[tid + 512] = f2b(x2 * inv);
}

// ===== R21: OCCUPANCY round — 512-thr blocks, 2x4 waves, 96-reg acc =======
// R16/R19/R20 all pinned at MfmaUtil 27-29% & Occupancy ~20% regardless of
// sync structure (single/double buffer, issue-early: all neutral). The
// invariant was the 4-wave block with 192-reg acc -> ~1.6 waves/SIMD, so
// read-phase and MFMA-phase serialize per CU (m114: overlap comes from
// OTHER waves). Single change: 512 threads, wave grid 2x4, per-wave tile
// 64x32 per z -> acc 96 regs/wave, ~190 total; __launch_bounds__(512,8)
// (reg ceiling 256) -> up to 8 waves/SIMD; LDS 32KB x 4 resident blocks =
// 128KB <= 160KB. Whole grid (1024 blocks = 4/CU) co-resident.
// Frozen from R19/R20: n-owned XCD supertile (FETCH 40MB ~= ideal),
// chunk^((row>>1)&3) swizzle (0 conflicts), z-staged reads, 2-barrier loop,
// fused epilogue.
__launch_bounds__(512, 8)
__global__ void gemm_rowsum(const unsigned short* nb, char* ws) {
    float* F = (float*)ws;
    const unsigned int* I = (const unsigned int*)ws;
    const uint2* RM = (const uint2*)(I + O_RM);
    int bid = blockIdx.x;
    int xcd = bid & 7, local = bid >> 3;                // 8 XCDs x 128 tiles
    int n0 = (xcd * 4 + (local & 3)) * 128;             // 4 n-panels per XCD (B L2-resident)
    int m0 = (local >> 2) * 128;                        // n-inner, m-major
    int tid = threadIdx.x, lane = tid & 63, wave = tid >> 6;
    int wm = (wave >> 2) * 64, wn = (wave & 3) * 32;    // 2x4 waves, 64x32/wave/z
    int lid = lane & 15, q = lane >> 4;
    __shared__ __align__(16) unsigned short L[4][4096];  // A,B0,B1,B2 = 32 KB

    // staging: thread t ∈ [0,512) covers all 512 16B-chunks of each region:
    // row = t>>2, chunk = t&3; LDS linear dest (= base + lane*16), source
    // chunk pre-swizzled (both-sides-or-neither rule).
    int row0 = tid >> 2, ch = tid & 3;
    int cs = (ch ^ ((row0 >> 1) & 3)) * 8;
    const unsigned short* gA  = nb + (size_t)(m0 + row0) * Dd + cs;
    const unsigned short* gB0 = nb + (size_t)(n0 + row0) * Dd + cs;
    const unsigned short* gB1 = gB0 + (size_t)Bn * Dd;
    const unsigned short* gB2 = gB1 + (size_t)Bn * Dd;

    // frag-read swizzle: r = base + i*16 + lid -> (r>>1)&3 == (lid>>1)&3
    int cswz = (q ^ ((lid >> 1) & 3)) * 8;

    f32x4 a0[4][2] = {}, a1[4][2] = {}, a2[4][2] = {};

#define STAGE(kt) { \
    gl_lds16(gA  + (kt) * 32, &L[0][tid * 8]); \
    gl_lds16(gB0 + (kt) * 32, &L[1][tid * 8]); \
    gl_lds16(gB1 + (kt) * 32, &L[2][tid * 8]); \
    gl_lds16(gB2 + (kt) * 32, &L[3][tid * 8]); \
}

    for (int kt = 0; kt < 24; ++kt) {
        __syncthreads();          // prev tile fully consumed (lgkm drained)
        STAGE(kt);
        __syncthreads();          // publish (vmcnt drained by syncthreads)
        // ---- z-staged reads: af+bf0+bf1 now, bf2 under z0's MFMAs ----
        sh8 af[4], bf0[2], bf1[2], bf2[2];
        #pragma unroll
        for (int i = 0; i < 4; ++i)
            af[i] = *(const sh8*)&L[0][(wm + i * 16 + lid) * 32 + cswz];
        #pragma unroll
        for (int j = 0; j < 2; ++j)
            bf0[j] = *(const sh8*)&L[1][(wn + j * 16 + lid) * 32 + cswz];
        #pragma unroll
        for (int j = 0; j < 2; ++j)
            bf1[j] = *(const sh8*)&L[2][(wn + j * 16 + lid) * 32 + cswz];
        __builtin_amdgcn_sched_barrier(0);
        __builtin_amdgcn_s_setprio(1);
        #pragma unroll
        for (int i = 0; i < 4; ++i)
            #pragma unroll
            for (int j = 0; j < 2; ++j)
                a0[i][j] = __builtin_amdgcn_mfma_f32_16x16x32_bf16(af[i], bf0[j], a0[i][j], 0, 0, 0);
        __builtin_amdgcn_s_setprio(0);
        __builtin_amdgcn_sched_barrier(0);
        #pragma unroll
        for (int j = 0; j < 2; ++j)
            bf2[j] = *(const sh8*)&L[3][(wn + j * 16 + lid) * 32 + cswz];
        __builtin_amdgcn_sched_barrier(0);
        __builtin_amdgcn_s_setprio(1);
        #pragma unroll
        for (int i = 0; i < 4; ++i)
            #pragma unroll
            for (int j = 0; j < 2; ++j)
                a1[i][j] = __builtin_amdgcn_mfma_f32_16x16x32_bf16(af[i], bf1[j], a1[i][j], 0, 0, 0);
        __builtin_amdgcn_s_setprio(0);
        __builtin_amdgcn_sched_barrier(0);
        __builtin_amdgcn_s_setprio(1);
        #pragma unroll
        for (int i = 0; i < 4; ++i)
            #pragma unroll
            for (int j = 0; j < 2; ++j)
                a2[i][j] = __builtin_amdgcn_mfma_f32_16x16x32_bf16(af[i], bf2[j], a2[i][j], 0, 0, 0);
        __builtin_amdgcn_s_setprio(0);
    }

    // ---- fused epilogue: 3 row sums, 2 masked sums, single uint4 pair store
    uint2 rmc[2];
    #pragma unroll
    for (int j = 0; j < 2; ++j) rmc[j] = RM[n0 + wn + j * 16 + lid];
    uint4* Lq = (uint4*)(ws + LIST_OFF);
    #pragma unroll
    for (int i = 0; i < 4; ++i)
        #pragma unroll
        for (int reg = 0; reg < 4; ++reg) {
            int grow = m0 + wm + i * 16 + q * 4 + reg;
            uint2 rm = RM[grow];
            unsigned int trow = rm.x & 255u, rsb = rm.y;
            float rs0 = 0.f, rs1 = 0.f, rs2 = 0.f, msOA = 0.f, msG = 0.f;
            #pragma unroll
            for (int j = 0; j < 2; ++j) {
                int gcol = n0 + wn + j * 16 + lid;
                float x0 = a0[i][j][reg] * SC2;
                float x1 = a1[i][j][reg] * SC2;
                float x2 = a2[i][j][reg] * SC2;
                float e0 = exp2f(x0);
                float e1 = exp2f(x1);
                float e2 = exp2f(x2);
                if (gcol == grow) e0 = 0.f;   // ori diagonal excluded from sums
                rs0 += e0; rs1 += e1; rs2 += e2;
                if ((rmc[j].x & 255u) == trow) {
                    msOA += e0 + e2;
                    msG  += e1;
                    unsigned int slot = rsb + (rmc[j].x >> 8);
                    if (slot < LCAP)
                        Lq[slot] = make_uint4((unsigned)grow, __float_as_uint(x0),
                                              __float_as_uint(x1), __float_as_uint(x2));
                }
            }
            #pragma unroll
            for (int off = 1; off < 16; off <<= 1) {
                rs0 += __shfl_xor(rs0, off);
                rs1 += __shfl_xor(rs1, off);
                rs2 += __shfl_xor(rs2, off);
                msOA += __shfl_xor(msOA, off);
                msG  += __shfl_xor(msG, off);
            }
            if (lid == 0) {
                atomicAdd(&F[O_S + grow], rs0);
                atomicAdd(&F[O_S + Bn + grow], rs1);
                atomicAdd(&F[O_S + 2 * Bn + grow], rs2);
                atomicAdd(&F[O_SMOA + grow], msOA);
                atomicAdd(&F[O_SMG + grow], msG);
            }
        }
}

// ---- flat loss pass: inline denominators, scaled atomic into d_out ----
__launch_bounds__(256)
__global__ void loss_kernel(char* ws, float* out) {
    float* F = (float*)ws;
    const unsigned int* I = (const unsigned int*)ws;
    const uint4* L = (const uint4*)(ws + LIST_OFF);
    unsigned int n = I[O_P]; if (n > LCAP) n = LCAP;
    float a0 = 0.f, a1 = 0.f;
    unsigned int stride = gridDim.x * 256;
    for (unsigned int idx = blockIdx.x * 256 + threadIdx.x; idx < n; idx += stride) {
        uint4 en = L[idx];
        int i = (int)en.x;
        float son = F[O_S + i], sgen = F[O_S + Bn + i], saug = F[O_S + 2 * Bn + i];
        float dco = (son + saug - F[O_SMOA + i]) + sgen + EPSF;
        float dad = (sgen - F[O_SMG + i]) + saug + son + DG + EPSF;
        float eo = exp2f(__uint_as_float(en.y));
        float eg = exp2f(__uint_as_float(en.z));
        float ea = exp2f(__uint_as_float(en.w));
        a0 += -__logf(eg / (eg + dad) + EPSF);
        a1 += -__logf(eo / (eo + dco) + EPSF) - __logf(ea / (ea + dco) + EPSF);
    }
    #pragma unroll
    for (int off = 1; off < 64; off <<= 1) { a0 += __shfl_xor(a0, off); a1 += __shfl_xor(a1, off); }
    __shared__ float r0[4], r1[4];
    int tid = threadIdx.x;
    if ((tid & 63) == 0) { r0[tid >> 6] = a0; r1[tid >> 6] = a1; }
    __syncthreads();
    if (tid == 0) {
        atomicAdd(&out[0], (r0[0] + r0[1] + r0[2] + r0[3]) * (1.0f / Bn));  // ad_loss
        atomicAdd(&out[1], (r1[0] + r1[1] + r1[2] + r1[3]) * (1.0f / Bn));  // co_loss
    }
}

extern "C" void kernel_launch(void* const* d_in, const int* in_sizes, int n_in,
                              void* d_out, int out_size, void* d_ws, size_t ws_size,
                              hipStream_t stream) {
    const float* f0 = (const float*)d_in[0];
    const float* f1 = (const float*)d_in[1];
    const float* f2 = (const float*)d_in[2];
    const int* tg = (const int*)d_in[3];
    char* ws = (char*)d_ws;
    unsigned int* I = (unsigned int*)d_ws;
    unsigned short* nb = (unsigned short*)(ws + NB_OFF);
    float* out = (float*)d_out;

    norm_sort_kernel<<<dim3(Bn + 1, 3), 256, 0, stream>>>(f0, f1, f2, nb, tg, I, out);
    gemm_rowsum<<<dim3(1024), 512, 0, stream>>>(nb, ws);
    loss_kernel<<<256, 256, 0, stream>>>(ws, out);
}

// Round 9
// 268.339 us; speedup vs baseline: 5.4546x; 5.4546x over previous
//
#include <hip/hip_runtime.h>
#include <hip/hip_bf16.h>
#include <math.h>

#define Bn 4096
#define Dd 768
#define SC2 28.85390081777927f   // 20 * log2(e): logits kept in base-2 domain
#define EPSF 1e-6f
#define DG 4.8516519541e8f       // expf(20.0f): exact exp_ori diagonal

// ws layout (4-byte elements)
#define O_S      0        // 3*4096 row sums (ori_nodiag, gen, aug)
#define O_SMOA   12288    // same-masked (ori_nodiag + aug) sums
#define O_SMG    16384    // same-masked gen sums
#define ZERO_F   20480    // floats to zero (covers all atomic sums)
#define O_P      20480    // uint: total pairs (= sum cnt^2)
#define O_RM     20608    // uint2[4096]: {tg | rank<<8, rowSlotBase}
#define LIST_OFF   262144      // byte offset: LCAP uint4 pair entries {row,x0,x1,x2}
#define LCAP       (1u << 19)
#define NB_OFF     33554432    // byte offset: bf16 normalized rows on|gn|an

typedef __attribute__((ext_vector_type(8))) short sh8;
typedef __attribute__((ext_vector_type(4))) float f32x4;

#define AS1 __attribute__((address_space(1)))
#define AS3 __attribute__((address_space(3)))

static __device__ __forceinline__ void gl_lds16(const void* g, void* l) {
    __builtin_amdgcn_global_load_lds((const AS1 void*)g, (AS3 void*)l, 16, 0, 0);
}

static __device__ __forceinline__ unsigned short f2b(float f) {
    unsigned int u = __float_as_uint(f);
    unsigned int r = (u + 0x7fffu + ((u >> 16) & 1u)) >> 16;  // RNE
    return (unsigned short)r;
}

// ---- normalize rows (blocks x<4096) + class sort (block x==4096,y==0) ----
__global__ void norm_sort_kernel(const float* f0, const float* f1, const float* f2,
                                 unsigned short* nb, const int* tg, unsigned int* I,
                                 float* out) {
    int r = blockIdx.x, m = blockIdx.y, tid = threadIdx.x;
    if (r == Bn) {
        if (m != 0) return;
        // ---- sort body (256 threads) ----
        float* F = (float*)I;
        __shared__ unsigned int h[128], pb[128], cur[128];
        for (int e = tid; e < ZERO_F; e += 256) F[e] = 0.f;
        if (tid == 0) { out[0] = 0.f; out[1] = 0.f; }
        if (tid < 128) { h[tid] = 0; cur[tid] = 0; }
        __syncthreads();
        for (int e = tid; e < Bn; e += 256) atomicAdd(&h[tg[e]], 1u);
        __syncthreads();
        if (tid < 128) pb[tid] = h[tid] * h[tid];
        __syncthreads();
        for (int s = 1; s < 128; s <<= 1) {
            unsigned int b = 0;
            if (tid < 128 && tid >= s) b = pb[tid - s];
            __syncthreads();
            if (tid < 128) pb[tid] += b;
            __syncthreads();
        }
        if (tid == 127) I[O_P] = pb[127];
        uint2* RM = (uint2*)(I + O_RM);
        for (int e = tid; e < Bn; e += 256) {
            int c = tg[e];
            unsigned int rk = atomicAdd(&cur[c], 1u);
            unsigned int n = h[c];
            RM[e] = make_uint2((unsigned)c | (rk << 8), (pb[c] - n * n) + rk * n);
        }
        return;
    }
    const float* src = (m == 0 ? f0 : (m == 1 ? f1 : f2)) + (size_t)r * Dd;
    float x0 = src[tid], x1 = src[tid + 256], x2 = src[tid + 512];
    float v = x0 * x0 + x1 * x1 + x2 * x2;
    #pragma unroll
    for (int off = 1; off < 64; off <<= 1) v += __shfl_xor(v, off);
    __shared__ float wr[4];
    if ((tid & 63) == 0) wr[tid >> 6] = v;
    __syncthreads();
    float inv = rsqrtf(wr[0] + wr[1] + wr[2] + wr[3]);
    unsigned short* dst = nb + ((size_t)m * Bn + r) * Dd;
    dst[tid] = f2b(x0 * inv);
    dst[tid + 256] = f2b(x1 * inv);
    dst[tid + 512] = f2b(x2 * inv);
}

// ===== R22: 3-blocks/CU via 96-reg acc (128m x 64n block, 2x2 waves) ======
// R21 failed on launch-bounds arithmetic: per-SIMD reg pool is 512 (m69:
// waves halve at 64/128/256), so (512,8) demanded 64 regs -> acc spilled
// (VGPR_Count 32, 6.7GB scratch). Correct version of the same occupancy
// theory: per-wave tile 64x32 per z -> acc 96 regs; ~155 live total fits
// __launch_bounds__(256,3)'s 170-reg cap -> 3 waves/SIMD -> 3 blocks/CU
// (12 waves/CU, was 8). Block tile 128m x 64n minimizes LDS reads at this
// acc size: af[4]+bf[2]x3 = 10 ds_read_b128/wave/kt; LDS 20KB/block.
// Frozen from R19: n-owned XCD supertile (adapted: XCD owns 8 64-wide
// n-tiles = same 4-panel B working set, L2-resident; FETCH stays ~ideal),
// chunk^((row>>1)&3) swizzle (0 conflicts), 2-syncthreads loop (all
// pipelining variants measured neutral), z-staged reads, fused epilogue.
__launch_bounds__(256, 3)
__global__ void gemm_rowsum(const unsigned short* nb, char* ws) {
    float* F = (float*)ws;
    const unsigned int* I = (const unsigned int*)ws;
    const uint2* RM = (const uint2*)(I + O_RM);
    int bid = blockIdx.x;
    int xcd = bid & 7, local = bid >> 3;                // 8 XCDs x 256 tiles
    int n0 = (xcd * 8 + (local & 7)) * 64;              // 8 n-tiles/XCD (B L2-resident)
    int m0 = (local >> 3) * 128;                        // n-inner, m-major
    int tid = threadIdx.x, lane = tid & 63, wave = tid >> 6;
    int wm = (wave >> 1) * 64, wn = (wave & 1) * 32;    // 2x2 waves, 64x32/wave/z
    int lid = lane & 15, q = lane >> 4;
    __shared__ __align__(16) unsigned short As[128 * 32];     // 8 KB
    __shared__ __align__(16) unsigned short Bs[3][64 * 32];   // 3 x 4 KB

    // staging: thread -> (row = tid>>2, chunk = tid&3). A covers rows
    // {row0, row0+64} (2 loads), each B region rows row0 (1 load).
    // LDS linear dest, source chunk pre-swizzled (both-sides-or-neither);
    // (row0+64)>>1 & 3 == (row0>>1)&3, so one cs serves both A loads.
    int row0 = tid >> 2, ch = tid & 3;
    int cs = (ch ^ ((row0 >> 1) & 3)) * 8;
    const unsigned short* gA  = nb + (size_t)(m0 + row0) * Dd + cs;
    const unsigned short* gB0 = nb + (size_t)(n0 + row0) * Dd + cs;
    const unsigned short* gB1 = gB0 + (size_t)Bn * Dd;
    const unsigned short* gB2 = gB1 + (size_t)Bn * Dd;

    // frag-read swizzle: r = base + i*16 + lid -> (r>>1)&3 == (lid>>1)&3
    int cswz = (q ^ ((lid >> 1) & 3)) * 8;

    f32x4 a0[4][2] = {}, a1[4][2] = {}, a2[4][2] = {};   // 96 regs total

    for (int kt = 0; kt < 24; ++kt) {
        __syncthreads();          // prev tile fully consumed
        gl_lds16(gA + kt * 32, &As[tid * 8]);
        gl_lds16(gA + (size_t)64 * Dd + kt * 32, &As[(tid + 256) * 8]);
        gl_lds16(gB0 + kt * 32, &Bs[0][tid * 8]);
        gl_lds16(gB1 + kt * 32, &Bs[1][tid * 8]);
        gl_lds16(gB2 + kt * 32, &Bs[2][tid * 8]);
        __syncthreads();          // publish (vmcnt+lgkm drained)
        // ---- z-staged reads: af+bf0 now, bf1 under z0, bf2 under z1 ----
        sh8 af[4], bf0[2], bf1[2], bf2[2];
        #pragma unroll
        for (int i = 0; i < 4; ++i)
            af[i] = *(const sh8*)&As[(wm + i * 16 + lid) * 32 + cswz];
        #pragma unroll
        for (int j = 0; j < 2; ++j)
            bf0[j] = *(const sh8*)&Bs[0][(wn + j * 16 + lid) * 32 + cswz];
        __builtin_amdgcn_sched_barrier(0);
        __builtin_amdgcn_s_setprio(1);
        #pragma unroll
        for (int i = 0; i < 4; ++i)
            #pragma unroll
            for (int j = 0; j < 2; ++j)
                a0[i][j] = __builtin_amdgcn_mfma_f32_16x16x32_bf16(af[i], bf0[j], a0[i][j], 0, 0, 0);
        __builtin_amdgcn_s_setprio(0);
        __builtin_amdgcn_sched_barrier(0);
        #pragma unroll
        for (int j = 0; j < 2; ++j)
            bf1[j] = *(const sh8*)&Bs[1][(wn + j * 16 + lid) * 32 + cswz];
        __builtin_amdgcn_sched_barrier(0);
        __builtin_amdgcn_s_setprio(1);
        #pragma unroll
        for (int i = 0; i < 4; ++i)
            #pragma unroll
            for (int j = 0; j < 2; ++j)
                a1[i][j] = __builtin_amdgcn_mfma_f32_16x16x32_bf16(af[i], bf1[j], a1[i][j], 0, 0, 0);
        __builtin_amdgcn_s_setprio(0);
        __builtin_amdgcn_sched_barrier(0);
        #pragma unroll
        for (int j = 0; j < 2; ++j)
            bf2[j] = *(const sh8*)&Bs[2][(wn + j * 16 + lid) * 32 + cswz];
        __builtin_amdgcn_sched_barrier(0);
        __builtin_amdgcn_s_setprio(1);
        #pragma unroll
        for (int i = 0; i < 4; ++i)
            #pragma unroll
            for (int j = 0; j < 2; ++j)
                a2[i][j] = __builtin_amdgcn_mfma_f32_16x16x32_bf16(af[i], bf2[j], a2[i][j], 0, 0, 0);
        __builtin_amdgcn_s_setprio(0);
    }

    // ---- fused epilogue: 3 row sums, 2 masked sums, single uint4 pair store
    uint2 rmc[2];
    #pragma unroll
    for (int j = 0; j < 2; ++j) rmc[j] = RM[n0 + wn + j * 16 + lid];
    uint4* Lq = (uint4*)(ws + LIST_OFF);
    #pragma unroll
    for (int i = 0; i < 4; ++i)
        #pragma unroll
        for (int reg = 0; reg < 4; ++reg) {
            int grow = m0 + wm + i * 16 + q * 4 + reg;
            uint2 rm = RM[grow];
            unsigned int trow = rm.x & 255u, rsb = rm.y;
            float rs0 = 0.f, rs1 = 0.f, rs2 = 0.f, msOA = 0.f, msG = 0.f;
            #pragma unroll
            for (int j = 0; j < 2; ++j) {
                int gcol = n0 + wn + j * 16 + lid;
                float x0 = a0[i][j][reg] * SC2;
                float x1 = a1[i][j][reg] * SC2;
                float x2 = a2[i][j][reg] * SC2;
                float e0 = exp2f(x0);
                float e1 = exp2f(x1);
                float e2 = exp2f(x2);
                if (gcol == grow) e0 = 0.f;   // ori diagonal excluded from sums
                rs0 += e0; rs1 += e1; rs2 += e2;
                if ((rmc[j].x & 255u) == trow) {
                    msOA += e0 + e2;
                    msG  += e1;
                    unsigned int slot = rsb + (rmc[j].x >> 8);
                    if (slot < LCAP)
                        Lq[slot] = make_uint4((unsigned)grow, __float_as_uint(x0),
                                              __float_as_uint(x1), __float_as_uint(x2));
                }
            }
            #pragma unroll
            for (int off = 1; off < 16; off <<= 1) {
                rs0 += __shfl_xor(rs0, off);
                rs1 += __shfl_xor(rs1, off);
                rs2 += __shfl_xor(rs2, off);
                msOA += __shfl_xor(msOA, off);
                msG  += __shfl_xor(msG, off);
            }
            if (lid == 0) {
                atomicAdd(&F[O_S + grow], rs0);
                atomicAdd(&F[O_S + Bn + grow], rs1);
                atomicAdd(&F[O_S + 2 * Bn + grow], rs2);
                atomicAdd(&F[O_SMOA + grow], msOA);
                atomicAdd(&F[O_SMG + grow], msG);
            }
        }
}

// ---- flat loss pass: inline denominators, scaled atomic into d_out ----
__launch_bounds__(256)
__global__ void loss_kernel(char* ws, float* out) {
    float* F = (float*)ws;
    const unsigned int* I = (const unsigned int*)ws;
    const uint4* L = (const uint4*)(ws + LIST_OFF);
    unsigned int n = I[O_P]; if (n > LCAP) n = LCAP;
    float a0 = 0.f, a1 = 0.f;
    unsigned int stride = gridDim.x * 256;
    for (unsigned int idx = blockIdx.x * 256 + threadIdx.x; idx < n; idx += stride) {
        uint4 en = L[idx];
        int i = (int)en.x;
        float son = F[O_S + i], sgen = F[O_S + Bn + i], saug = F[O_S + 2 * Bn + i];
        float dco = (son + saug - F[O_SMOA + i]) + sgen + EPSF;
        float dad = (sgen - F[O_SMG + i]) + saug + son + DG + EPSF;
        float eo = exp2f(__uint_as_float(en.y));
        float eg = exp2f(__uint_as_float(en.z));
        float ea = exp2f(__uint_as_float(en.w));
        a0 += -__logf(eg / (eg + dad) + EPSF);
        a1 += -__logf(eo / (eo + dco) + EPSF) - __logf(ea / (ea + dco) + EPSF);
    }
    #pragma unroll
    for (int off = 1; off < 64; off <<= 1) { a0 += __shfl_xor(a0, off); a1 += __shfl_xor(a1, off); }
    __shared__ float r0[4], r1[4];
    int tid = threadIdx.x;
    if ((tid & 63) == 0) { r0[tid >> 6] = a0; r1[tid >> 6] = a1; }
    __syncthreads();
    if (tid == 0) {
        atomicAdd(&out[0], (r0[0] + r0[1] + r0[2] + r0[3]) * (1.0f / Bn));  // ad_loss
        atomicAdd(&out[1], (r1[0] + r1[1] + r1[2] + r1[3]) * (1.0f / Bn));  // co_loss
    }
}

extern "C" void kernel_launch(void* const* d_in, const int* in_sizes, int n_in,
                              void* d_out, int out_size, void* d_ws, size_t ws_size,
                              hipStream_t stream) {
    const float* f0 = (const float*)d_in[0];
    const float* f1 = (const float*)d_in[1];
    const float* f2 = (const float*)d_in[2];
    const int* tg = (const int*)d_in[3];
    char* ws = (char*)d_ws;
    unsigned int* I = (unsigned int*)d_ws;
    unsigned short* nb = (unsigned short*)(ws + NB_OFF);
    float* out = (float*)d_out;

    norm_sort_kernel<<<dim3(Bn + 1, 3), 256, 0, stream>>>(f0, f1, f2, nb, tg, I, out);
    gemm_rowsum<<<dim3(2048), 256, 0, stream>>>(nb, ws);
    loss_kernel<<<256, 256, 0, stream>>>(ws, out);
}

// Round 11
// 197.530 us; speedup vs baseline: 7.4099x; 1.3585x over previous
//
#include <hip/hip_runtime.h>
#include <hip/hip_bf16.h>
#include <math.h>

#define Bn 4096
#define Dd 768
#define SC2 28.85390081777927f   // 20 * log2(e): logits kept in base-2 domain
#define EPSF 1e-6f
#define DG 4.8516519541e8f       // expf(20.0f): exact exp_ori diagonal

// ws layout (4-byte elements)
#define O_S      0        // 3*4096 row sums (ori_nodiag, gen, aug)
#define O_SMOA   12288    // same-masked (ori_nodiag + aug) sums
#define O_SMG    16384    // same-masked gen sums
#define ZERO_F   20480    // floats to zero (covers all atomic sums)
#define O_P      20480    // uint: total pairs (= sum cnt^2)
#define O_RM     20608    // uint2[4096]: {tg | rank<<8, rowSlotBase}
#define LIST_OFF   262144      // byte offset: LCAP uint4 pair entries {row,x0,x1,x2}
#define LCAP       (1u << 19)
#define NB_OFF     33554432    // byte offset: bf16 normalized rows on|gn|an

typedef __attribute__((ext_vector_type(8))) short sh8;
typedef __attribute__((ext_vector_type(4))) float f32x4;

#define AS1 __attribute__((address_space(1)))
#define AS3 __attribute__((address_space(3)))

static __device__ __forceinline__ void gl_lds16(const void* g, void* l) {
    __builtin_amdgcn_global_load_lds((const AS1 void*)g, (AS3 void*)l, 16, 0, 0);
}

static __device__ __forceinline__ unsigned short f2b(float f) {
    unsigned int u = __float_as_uint(f);
    unsigned int r = (u + 0x7fffu + ((u >> 16) & 1u)) >> 16;  // RNE
    return (unsigned short)r;
}

// ---- normalize rows (blocks x<4096) + class sort (block x==4096,y==0) ----
__global__ void norm_sort_kernel(const float* f0, const float* f1, const float* f2,
                                 unsigned short* nb, const int* tg, unsigned int* I,
                                 float* out) {
    int r = blockIdx.x, m = blockIdx.y, tid = threadIdx.x;
    if (r == Bn) {
        if (m != 0) return;
        // ---- sort body (256 threads) ----
        float* F = (float*)I;
        __shared__ unsigned int h[128], pb[128], cur[128];
        for (int e = tid; e < ZERO_F; e += 256) F[e] = 0.f;
        if (tid == 0) { out[0] = 0.f; out[1] = 0.f; }
        if (tid < 128) { h[tid] = 0; cur[tid] = 0; }
        __syncthreads();
        for (int e = tid; e < Bn; e += 256) atomicAdd(&h[tg[e]], 1u);
        __syncthreads();
        if (tid < 128) pb[tid] = h[tid] * h[tid];
        __syncthreads();
        for (int s = 1; s < 128; s <<= 1) {
            unsigned int b = 0;
            if (tid < 128 && tid >= s) b = pb[tid - s];
            __syncthreads();
            if (tid < 128) pb[tid] += b;
            __syncthreads();
        }
        if (tid == 127) I[O_P] = pb[127];
        uint2* RM = (uint2*)(I + O_RM);
        for (int e = tid; e < Bn; e += 256) {
            int c = tg[e];
            unsigned int rk = atomicAdd(&cur[c], 1u);
            unsigned int n = h[c];
            RM[e] = make_uint2((unsigned)c | (rk << 8), (pb[c] - n * n) + rk * n);
        }
        return;
    }
    const float* src = (m == 0 ? f0 : (m == 1 ? f1 : f2)) + (size_t)r * Dd;
    float x0 = src[tid], x1 = src[tid + 256], x2 = src[tid + 512];
    float v = x0 * x0 + x1 * x1 + x2 * x2;
    #pragma unroll
    for (int off = 1; off < 64; off <<= 1) v += __shfl_xor(v, off);
    __shared__ float wr[4];
    if ((tid & 63) == 0) wr[tid >> 6] = v;
    __syncthreads();
    float inv = rsqrtf(wr[0] + wr[1] + wr[2] + wr[3]);
    unsigned short* dst = nb + ((size_t)m * Bn + r) * Dd;
    dst[tid] = f2b(x0 * inv);
    dst[tid + 256] = f2b(x1 * inv);
    dst[tid + 512] = f2b(x2 * inv);
}

// ===== R23 (resubmit; R10 was an infra failure): R19 with BK=64 ===========
// R22 post-mortem: (256,3) reg-cap pushed acc out of VGPRs again + smaller
// tile doubled per-element epilogue cost -> 180us. Conclusion from
// R16/R19/R20/R22: at the proven config every residency/buffering variant
// is neutral-or-worse; the measured ~2850cy/kt vs 931 MFMA + 770 LDS-read
// means the {2 barriers + vmcnt drain + stage-issue} tax (~700-900cy) is
// paid 24x. This round halves the COUNT of that tax: BK=64, two 32-k
// slices staged per sync pair, per-slice compute body identical to R19.
// LDS 64KB: R18 measured the same footprint at ~20.7% occupancy (2 blk/CU)
// -> residency-neutral (R17's loss was 96KB, not 64). Everything else
// frozen: n-owned XCD map (FETCH~=ideal 40MB), chunk^((row>>1)&3) swizzle
// (0 conflicts), z-staged reads + setprio, fused epilogue.
__launch_bounds__(256, 2)
__global__ void gemm_rowsum(const unsigned short* nb, char* ws) {
    float* F = (float*)ws;
    const unsigned int* I = (const unsigned int*)ws;
    const uint2* RM = (const uint2*)(I + O_RM);
    int bid = blockIdx.x;
    int xcd = bid & 7, local = bid >> 3;                // 8 XCDs x 128 tiles
    int n0 = (xcd * 4 + (local & 3)) * 128;             // 4 n-panels per XCD (B L2-resident)
    int m0 = (local >> 2) * 128;                        // n-inner, m-major
    int tid = threadIdx.x, lane = tid & 63, wave = tid >> 6;
    int wm = (wave >> 1) * 64, wn = (wave & 1) * 64;    // 2x2 waves, 64x64/wave/z
    int lid = lane & 15, q = lane >> 4;
    __shared__ __align__(16) unsigned short As[2][128 * 32];     // 16 KB
    __shared__ __align__(16) unsigned short Bs[3][2][128 * 32];  // 48 KB

    // staging: thread -> (row = tid>>2, chunk = tid&3); rows 0..63 load0,
    // 64..127 load1 ((row+64)>>1 & 3 unchanged). LDS linear dest,
    // source chunk pre-swizzled (both-sides-or-neither rule).
    int row0 = tid >> 2, ch = tid & 3;
    int cs = (ch ^ ((row0 >> 1) & 3)) * 8;
    const unsigned short* gA  = nb + (size_t)(m0 + row0) * Dd + cs;
    const unsigned short* gB0 = nb + (size_t)(n0 + row0) * Dd + cs;
    const unsigned short* gB1 = gB0 + (size_t)Bn * Dd;
    const unsigned short* gB2 = gB1 + (size_t)Bn * Dd;

    // frag-read swizzle: r = base + i*16 + lid -> (r>>1)&3 == (lid>>1)&3
    int cswz = (q ^ ((lid >> 1) & 3)) * 8;

    f32x4 a0[4][4] = {}, a1[4][4] = {}, a2[4][4] = {};

    for (int kp = 0; kp < 12; ++kp) {
        __syncthreads();          // prev pair fully consumed
        #pragma unroll
        for (int h = 0; h < 2; ++h) {
            int ko = kp * 64 + h * 32;
            gl_lds16(gA + ko, &As[h][tid * 8]);
            gl_lds16(gA + (size_t)64 * Dd + ko, &As[h][(tid + 256) * 8]);
            gl_lds16(gB0 + ko, &Bs[0][h][tid * 8]);
            gl_lds16(gB0 + (size_t)64 * Dd + ko, &Bs[0][h][(tid + 256) * 8]);
            gl_lds16(gB1 + ko, &Bs[1][h][tid * 8]);
            gl_lds16(gB1 + (size_t)64 * Dd + ko, &Bs[1][h][(tid + 256) * 8]);
            gl_lds16(gB2 + ko, &Bs[2][h][tid * 8]);
            gl_lds16(gB2 + (size_t)64 * Dd + ko, &Bs[2][h][(tid + 256) * 8]);
        }
        __syncthreads();          // publish (vmcnt+lgkm drained) — 12x not 24x
        #pragma unroll
        for (int h = 0; h < 2; ++h) {
            // ---- z-staged reads: af+bf0+bf1 now, bf2 under z0's MFMAs ----
            sh8 af[4], bf0[4], bf1[4], bf2[4];
            #pragma unroll
            for (int i = 0; i < 4; ++i)
                af[i] = *(const sh8*)&As[h][(wm + i * 16 + lid) * 32 + cswz];
            #pragma unroll
            for (int j = 0; j < 4; ++j)
                bf0[j] = *(const sh8*)&Bs[0][h][(wn + j * 16 + lid) * 32 + cswz];
            #pragma unroll
            for (int j = 0; j < 4; ++j)
                bf1[j] = *(const sh8*)&Bs[1][h][(wn + j * 16 + lid) * 32 + cswz];
            __builtin_amdgcn_sched_barrier(0);
            __builtin_amdgcn_s_setprio(1);
            #pragma unroll
            for (int i = 0; i < 4; ++i)
                #pragma unroll
                for (int j = 0; j < 4; ++j)
                    a0[i][j] = __builtin_amdgcn_mfma_f32_16x16x32_bf16(af[i], bf0[j], a0[i][j], 0, 0, 0);
            __builtin_amdgcn_s_setprio(0);
            __builtin_amdgcn_sched_barrier(0);
            #pragma unroll
            for (int j = 0; j < 4; ++j)
                bf2[j] = *(const sh8*)&Bs[2][h][(wn + j * 16 + lid) * 32 + cswz];
            __builtin_amdgcn_sched_barrier(0);
            __builtin_amdgcn_s_setprio(1);
            #pragma unroll
            for (int i = 0; i < 4; ++i)
                #pragma unroll
                for (int j = 0; j < 4; ++j)
                    a1[i][j] = __builtin_amdgcn_mfma_f32_16x16x32_bf16(af[i], bf1[j], a1[i][j], 0, 0, 0);
            __builtin_amdgcn_s_setprio(0);
            __builtin_amdgcn_sched_barrier(0);
            __builtin_amdgcn_s_setprio(1);
            #pragma unroll
            for (int i = 0; i < 4; ++i)
                #pragma unroll
                for (int j = 0; j < 4; ++j)
                    a2[i][j] = __builtin_amdgcn_mfma_f32_16x16x32_bf16(af[i], bf2[j], a2[i][j], 0, 0, 0);
            __builtin_amdgcn_s_setprio(0);
        }
    }

    // ---- fused epilogue: 3 row sums, 2 masked sums, single uint4 pair store
    uint2 rmc[4];
    #pragma unroll
    for (int j = 0; j < 4; ++j) rmc[j] = RM[n0 + wn + j * 16 + lid];
    uint4* Lq = (uint4*)(ws + LIST_OFF);
    #pragma unroll
    for (int i = 0; i < 4; ++i)
        #pragma unroll
        for (int reg = 0; reg < 4; ++reg) {
            int grow = m0 + wm + i * 16 + q * 4 + reg;
            uint2 rm = RM[grow];
            unsigned int trow = rm.x & 255u, rsb = rm.y;
            float rs0 = 0.f, rs1 = 0.f, rs2 = 0.f, msOA = 0.f, msG = 0.f;
            #pragma unroll
            for (int j = 0; j < 4; ++j) {
                int gcol = n0 + wn + j * 16 + lid;
                float x0 = a0[i][j][reg] * SC2;
                float x1 = a1[i][j][reg] * SC2;
                float x2 = a2[i][j][reg] * SC2;
                float e0 = exp2f(x0);
                float e1 = exp2f(x1);
                float e2 = exp2f(x2);
                if (gcol == grow) e0 = 0.f;   // ori diagonal excluded from sums
                rs0 += e0; rs1 += e1; rs2 += e2;
                if ((rmc[j].x & 255u) == trow) {
                    msOA += e0 + e2;
                    msG  += e1;
                    unsigned int slot = rsb + (rmc[j].x >> 8);
                    if (slot < LCAP)
                        Lq[slot] = make_uint4((unsigned)grow, __float_as_uint(x0),
                                              __float_as_uint(x1), __float_as_uint(x2));
                }
            }
            #pragma unroll
            for (int off = 1; off < 16; off <<= 1) {
                rs0 += __shfl_xor(rs0, off);
                rs1 += __shfl_xor(rs1, off);
                rs2 += __shfl_xor(rs2, off);
                msOA += __shfl_xor(msOA, off);
                msG  += __shfl_xor(msG, off);
            }
            if (lid == 0) {
                atomicAdd(&F[O_S + grow], rs0);
                atomicAdd(&F[O_S + Bn + grow], rs1);
                atomicAdd(&F[O_S + 2 * Bn + grow], rs2);
                atomicAdd(&F[O_SMOA + grow], msOA);
                atomicAdd(&F[O_SMG + grow], msG);
            }
        }
}

// ---- flat loss pass: inline denominators, scaled atomic into d_out ----
__launch_bounds__(256)
__global__ void loss_kernel(char* ws, float* out) {
    float* F = (float*)ws;
    const unsigned int* I = (const unsigned int*)ws;
    const uint4* L = (const uint4*)(ws + LIST_OFF);
    unsigned int n = I[O_P]; if (n > LCAP) n = LCAP;
    float a0 = 0.f, a1 = 0.f;
    unsigned int stride = gridDim.x * 256;
    for (unsigned int idx = blockIdx.x * 256 + threadIdx.x; idx < n; idx += stride) {
        uint4 en = L[idx];
        int i = (int)en.x;
        float son = F[O_S + i], sgen = F[O_S + Bn + i], saug = F[O_S + 2 * Bn + i];
        float dco = (son + saug - F[O_SMOA + i]) + sgen + EPSF;
        float dad = (sgen - F[O_SMG + i]) + saug + son + DG + EPSF;
        float eo = exp2f(__uint_as_float(en.y));
        float eg = exp2f(__uint_as_float(en.z));
        float ea = exp2f(__uint_as_float(en.w));
        a0 += -__logf(eg / (eg + dad) + EPSF);
        a1 += -__logf(eo / (eo + dco) + EPSF) - __logf(ea / (ea + dco) + EPSF);
    }
    #pragma unroll
    for (int off = 1; off < 64; off <<= 1) { a0 += __shfl_xor(a0, off); a1 += __shfl_xor(a1, off); }
    __shared__ float r0[4], r1[4];
    int tid = threadIdx.x;
    if ((tid & 63) == 0) { r0[tid >> 6] = a0; r1[tid >> 6] = a1; }
    __syncthreads();
    if (tid == 0) {
        atomicAdd(&out[0], (r0[0] + r0[1] + r0[2] + r0[3]) * (1.0f / Bn));  // ad_loss
        atomicAdd(&out[1], (r1[0] + r1[1] + r1[2] + r1[3]) * (1.0f / Bn));  // co_loss
    }
}

extern "C" void kernel_launch(void* const* d_in, const int* in_sizes, int n_in,
                              void* d_out, int out_size, void* d_ws, size_t ws_size,
                              hipStream_t stream) {
    const float* f0 = (const float*)d_in[0];
    const float* f1 = (const float*)d_in[1];
    const float* f2 = (const float*)d_in[2];
    const int* tg = (const int*)d_in[3];
    char* ws = (char*)d_ws;
    unsigned int* I = (unsigned int*)d_ws;
    unsigned short* nb = (unsigned short*)(ws + NB_OFF);
    float* out = (float*)d_out;

    norm_sort_kernel<<<dim3(Bn + 1, 3), 256, 0, stream>>>(f0, f1, f2, nb, tg, I, out);
    gemm_rowsum<<<dim3(1024), 256, 0, stream>>>(nb, ws);
    loss_kernel<<<256, 256, 0, stream>>>(ws, out);
}